// Round 1
// baseline (1740.193 us; speedup 1.0000x reference)
//
#include <hip/hip_runtime.h>
#include <math.h>

// Problem constants
#define NTOK 16384   // B*L
#define LSEQ 4096
#define BATCH 4
#define DDIM 512
#define PDIM 128
#define VDIM 8
#define PI_F 3.14159265358979323846f

// scan chunking
#define NC2 64            // chunks for (b,d) scans, chunk len 64
#define CL2 64
#define NC3 128           // chunks for kv scan, chunk len 32
#define CL3 32

__device__ __forceinline__ float sigmoid_(float v) { return 1.0f / (1.0f + expf(-v)); }
__device__ __forceinline__ float gelu_(float v) { return 0.5f * v * (1.0f + erff(v * 0.70710678118654752f)); }

// ---------------------------------------------------------------------------
// Generic fp32 tiled GEMM: C[r, colOff+c] = act(A[r,:] @ W[:,c] + bias[c]) (+res)
// A[r,k] = (k < Ksplit) ? A0[r*ldA0+k] : A1[r*ldA1+(k-Ksplit)]
// Tile 128x128, BK=16, 256 threads, 8x8 per thread. Requires N%128==0, M%128==0, K%16==0.
// ---------------------------------------------------------------------------
__global__ __launch_bounds__(256) void gemm_f32(
    const float* __restrict__ A0, int ldA0,
    const float* __restrict__ A1, int ldA1, int Ksplit,
    int K,
    const float* __restrict__ W, const float* __restrict__ bias, int M,
    float* __restrict__ C, int ldC, int colOff,
    const float* __restrict__ res, int ldRes,
    int act)
{
    __shared__ float As[16][132];
    __shared__ float Bs[16][132];
    const int tid = threadIdx.x;
    const int tx = tid & 15;
    const int ty = tid >> 4;
    const int row0 = blockIdx.y << 7;
    const int col0 = blockIdx.x << 7;

    float acc[8][8];
#pragma unroll
    for (int i = 0; i < 8; ++i)
#pragma unroll
        for (int j = 0; j < 8; ++j) acc[i][j] = 0.0f;

    for (int k0 = 0; k0 < K; k0 += 16) {
#pragma unroll
        for (int it = 0; it < 2; ++it) {
            int idx = tid + it * 256;      // 0..511
            int r = idx >> 2;              // 0..127
            int kq = idx & 3;              // 0..3
            int kk = k0 + kq * 4;
            const float* ap = (kk < Ksplit)
                ? (A0 + (size_t)(row0 + r) * ldA0 + kk)
                : (A1 + (size_t)(row0 + r) * ldA1 + (kk - Ksplit));
            float4 av = *(const float4*)ap;
            As[kq * 4 + 0][r] = av.x;
            As[kq * 4 + 1][r] = av.y;
            As[kq * 4 + 2][r] = av.z;
            As[kq * 4 + 3][r] = av.w;
        }
#pragma unroll
        for (int it = 0; it < 2; ++it) {
            int idx = tid + it * 256;
            int cq = idx & 31;             // 0..31
            int kk = idx >> 5;             // 0..15
            *(float4*)&Bs[kk][cq * 4] = *(const float4*)(W + (size_t)(k0 + kk) * M + col0 + cq * 4);
        }
        __syncthreads();
#pragma unroll
        for (int k = 0; k < 16; ++k) {
            float4 a0 = *(const float4*)&As[k][ty * 8];
            float4 a1 = *(const float4*)&As[k][ty * 8 + 4];
            float4 b0 = *(const float4*)&Bs[k][tx * 8];
            float4 b1 = *(const float4*)&Bs[k][tx * 8 + 4];
            float a[8] = {a0.x, a0.y, a0.z, a0.w, a1.x, a1.y, a1.z, a1.w};
            float b[8] = {b0.x, b0.y, b0.z, b0.w, b1.x, b1.y, b1.z, b1.w};
#pragma unroll
            for (int i = 0; i < 8; ++i)
#pragma unroll
                for (int j = 0; j < 8; ++j) acc[i][j] = fmaf(a[i], b[j], acc[i][j]);
        }
        __syncthreads();
    }

    float bv[8];
    {
        const float* bp = bias + col0 + tx * 8;
#pragma unroll
        for (int j = 0; j < 8; ++j) bv[j] = bp[j];
    }
#pragma unroll
    for (int i = 0; i < 8; ++i) {
        size_t r = (size_t)row0 + ty * 8 + i;
        float o[8];
#pragma unroll
        for (int j = 0; j < 8; ++j) {
            float v = acc[i][j] + bv[j];
            if (act == 1) v = gelu_(v);
            o[j] = v;
        }
        if (res) {
            const float* rp = res + r * ldRes + col0 + tx * 8;
            float4 r0 = *(const float4*)rp;
            float4 r1 = *(const float4*)(rp + 4);
            o[0] += r0.x; o[1] += r0.y; o[2] += r0.z; o[3] += r0.w;
            o[4] += r1.x; o[5] += r1.y; o[6] += r1.z; o[7] += r1.w;
        }
        float* cp = C + r * ldC + colOff + col0 + tx * 8;
        *(float4*)cp       = make_float4(o[0], o[1], o[2], o[3]);
        *(float4*)(cp + 4) = make_float4(o[4], o[5], o[6], o[7]);
    }
}

// ---------------------------------------------------------------------------
// cos/sin of pos_phases (L*D elements)
// ---------------------------------------------------------------------------
__global__ void k_phi(const float* __restrict__ pp, float* __restrict__ cphi,
                      float* __restrict__ sphi, int n)
{
    int i = blockIdx.x * 256 + threadIdx.x;
    if (i < n) {
        float s, c;
        sincosf(pp[i], &s, &c);
        cphi[i] = c;
        sphi[i] = s;
    }
}

// ---------------------------------------------------------------------------
// g_lin[r] = x[r,:] @ w_g + b_g   (one wave per row)
// ---------------------------------------------------------------------------
__global__ __launch_bounds__(256) void k_glin(const float* __restrict__ x,
                                              const float* __restrict__ wg,
                                              const float* __restrict__ bg,
                                              float* __restrict__ glin)
{
    int wid = threadIdx.x >> 6, lane = threadIdx.x & 63;
    int row = blockIdx.x * 4 + wid;
    const float4* xr = (const float4*)(x + (size_t)row * DDIM);
    const float4* w4 = (const float4*)wg;
    float4 a0 = xr[lane], a1 = xr[lane + 64];
    float4 w0 = w4[lane], w1 = w4[lane + 64];
    float p = a0.x * w0.x + a0.y * w0.y + a0.z * w0.z + a0.w * w0.w
            + a1.x * w1.x + a1.y * w1.y + a1.z * w1.z + a1.w * w1.w;
    for (int d = 32; d >= 1; d >>= 1) p += __shfl_down(p, d, 64);
    if (lane == 0) glin[row] = p + bg[0];
}

// ---------------------------------------------------------------------------
// gv[r,v] = (x[r,:] @ w_ve + b_ve)[v] * sigmoid(g_lin[r])
// ---------------------------------------------------------------------------
__global__ __launch_bounds__(256) void k_values(const float* __restrict__ x,
                                                const float* __restrict__ wve,
                                                const float* __restrict__ bve,
                                                const float* __restrict__ glin,
                                                float* __restrict__ gv)
{
    int g = blockIdx.x * 256 + threadIdx.x;   // N*V
    int m = g & 7, r = g >> 3;
    const float4* xr = (const float4*)(x + (size_t)r * DDIM);
    float acc = bve[m];
    for (int kq = 0; kq < 128; ++kq) {
        float4 a = xr[kq];
        int k = kq * 4;
        acc += a.x * wve[k * 8 + m] + a.y * wve[(k + 1) * 8 + m]
             + a.z * wve[(k + 2) * 8 + m] + a.w * wve[(k + 3) * 8 + m];
    }
    gv[g] = acc * sigmoid_(glin[r]);
}

// ---------------------------------------------------------------------------
// scan family 1: per (b,d) cumsums of {wv*cos, wv*sin, mag, x} — 3 passes
// ---------------------------------------------------------------------------
__global__ __launch_bounds__(256) void k_scan1a(
    const float* __restrict__ v1, const float* __restrict__ mlin,
    const float* __restrict__ x,
    const float* __restrict__ cphi, const float* __restrict__ sphi,
    const float* __restrict__ msp, float* __restrict__ sum2)
{
    int g = blockIdx.x * 256 + threadIdx.x;   // B*NC2*D = 131072
    int d = g & 511;
    int rest = g >> 9;
    int chunk = rest & (NC2 - 1);
    int b = rest >> 6;
    float msabs = fabsf(msp[0]);
    size_t base = ((size_t)b * LSEQ + chunk * CL2) * DDIM + d;
    size_t pbase = ((size_t)chunk * CL2) * DDIM + d;
    float ac = 0.f, as = 0.f, am = 0.f, ax = 0.f;
    for (int i = 0; i < CL2; ++i) {
        float ml = mlin[base], vv = v1[base], xv = x[base];
        float cp = cphi[pbase], sp = sphi[pbase];
        float mag = msabs * sigmoid_(ml);
        float wv = mag * vv;
        ac += wv * cp; as += wv * sp; am += mag; ax += xv;
        base += DDIM; pbase += DDIM;
    }
    int col = (b * DDIM + d) * NC2 + chunk;   // [b][d][chunk]
    sum2[0 * 131072 + col] = ac;
    sum2[1 * 131072 + col] = as;
    sum2[2 * 131072 + col] = am;
    sum2[3 * 131072 + col] = ax;
}

__global__ __launch_bounds__(256) void k_scan1b(float* __restrict__ sum2)
{
    int g = blockIdx.x * 256 + threadIdx.x;   // 4*B*D = 8192 rows of NC2
    float* p = sum2 + (size_t)g * NC2;
    float run = 0.f;
    for (int i = 0; i < NC2; ++i) { float t = p[i]; p[i] = run; run += t; }
}

__global__ __launch_bounds__(256) void k_scan1c(
    const float* __restrict__ v1, const float* __restrict__ mlin,
    const float* __restrict__ qlin, const float* __restrict__ x,
    const float* __restrict__ cphi, const float* __restrict__ sphi,
    const float* __restrict__ msp, const float* __restrict__ sum2,
    float* __restrict__ pret, float* __restrict__ ctx)
{
    int g = blockIdx.x * 256 + threadIdx.x;
    int d = g & 511;
    int rest = g >> 9;
    int chunk = rest & (NC2 - 1);
    int b = rest >> 6;
    float msabs = fabsf(msp[0]);
    int col = (b * DDIM + d) * NC2 + chunk;
    float ac = sum2[col];
    float as = sum2[131072 + col];
    float am = sum2[2 * 131072 + col];
    float ax = sum2[3 * 131072 + col];
    size_t base = ((size_t)b * LSEQ + chunk * CL2) * DDIM + d;
    size_t pbase = ((size_t)chunk * CL2) * DDIM + d;
    int l = chunk * CL2;
    const float rsd = 0.04419417382415922f;   // 1/sqrt(512)
    for (int i = 0; i < CL2; ++i, ++l) {
        float ml = mlin[base], vv = v1[base], xv = x[base], q = qlin[base];
        float cp = cphi[pbase], sp = sphi[pbase];
        float mag = msabs * sigmoid_(ml);
        float wv = mag * vv;
        ac += wv * cp; as += wv * sp; am += mag; ax += xv;
        float inv = rsqrtf(am + 1e-8f);
        float mc = ac * inv, msn = as * inv;
        float cq, sq;
        sincosf(q, &sq, &cq);
        float cpq = cp * cq - sp * sq;   // cos(phi+q)
        float spq = sp * cq + cp * sq;   // sin(phi+q)
        pret[base] = (mc * cpq + msn * spq) * rsd;
        ctx[base] = ax / (float)(l + 1);
        base += DDIM; pbase += DDIM;
    }
}

// ---------------------------------------------------------------------------
// phase tables: storage_phase (from sk) and query_phase (from ke_lin)
// ---------------------------------------------------------------------------
__global__ void k_phases(const float* __restrict__ sk, const float* __restrict__ ke,
                         float* __restrict__ csp, float* __restrict__ ssp,
                         float* __restrict__ cqp, float* __restrict__ sqp, int n)
{
    int g = blockIdx.x * 256 + threadIdx.x;
    if (g < n) {
        float s, c;
        float spv = tanhf(sk[g]) * PI_F;
        sincosf(spv, &s, &c);
        csp[g] = c; ssp[g] = s;
        float qpv = tanhf(ke[g]) * PI_F;
        sincosf(qpv, &s, &c);
        cqp[g] = c; sqp[g] = s;
    }
}

// ---------------------------------------------------------------------------
// gate cumsum per batch: block-parallel scan of sigmoid(g_lin) over L=4096
// ---------------------------------------------------------------------------
__global__ __launch_bounds__(1024) void k_gatescan(const float* __restrict__ glin,
                                                   float* __restrict__ gcum)
{
    __shared__ float s[1024];
    int b = blockIdx.x, tid = threadIdx.x;
    const float* gp = glin + (size_t)b * LSEQ + tid * 4;
    float e0 = sigmoid_(gp[0]);
    float e1 = sigmoid_(gp[1]);
    float e2 = sigmoid_(gp[2]);
    float e3 = sigmoid_(gp[3]);
    float l0 = e0, l1 = l0 + e1, l2 = l1 + e2, l3 = l2 + e3;
    s[tid] = l3;
    __syncthreads();
    for (int off = 1; off < 1024; off <<= 1) {
        float t = (tid >= off) ? s[tid - off] : 0.0f;
        __syncthreads();
        s[tid] += t;
        __syncthreads();
    }
    float excl = s[tid] - l3;
    float* out = gcum + (size_t)b * LSEQ + tid * 4;
    out[0] = excl + l0; out[1] = excl + l1; out[2] = excl + l2; out[3] = excl + l3;
}

// ---------------------------------------------------------------------------
// kv scan: state (P,V) per batch. Block = (b, chunk). Wave w owns v in
// {2w,2w+1}; lane owns 4 consecutive p. sum3 layout: [b][p][v][cs][chunk].
// ---------------------------------------------------------------------------
__device__ __forceinline__ size_t kv_sum_idx(int b, int p, int v) {
    return ((((size_t)b * PDIM + p) * VDIM + v) * 2) * NC3;
}

__global__ __launch_bounds__(256) void k_kv1(const float* __restrict__ csp,
                                             const float* __restrict__ ssp,
                                             const float* __restrict__ gv,
                                             float* __restrict__ sum3)
{
    int blk = blockIdx.x;                 // B*NC3 = 512
    int chunk = blk & (NC3 - 1), b = blk >> 7;
    int tid = threadIdx.x;
    int w = tid >> 6, lane = tid & 63;
    int v = 2 * w + (lane & 1);
    int pq = lane >> 1;                   // 0..31
    float sc[4] = {0, 0, 0, 0}, ss[4] = {0, 0, 0, 0};
    const float4* c4p = (const float4*)csp;
    const float4* s4p = (const float4*)ssp;
    int t = b * LSEQ + chunk * CL3;
    for (int i = 0; i < CL3; ++i, ++t) {
        float4 c4 = c4p[(size_t)t * 32 + pq];
        float4 s4 = s4p[(size_t)t * 32 + pq];
        float g = gv[(size_t)t * VDIM + v];
        sc[0] += c4.x * g; sc[1] += c4.y * g; sc[2] += c4.z * g; sc[3] += c4.w * g;
        ss[0] += s4.x * g; ss[1] += s4.y * g; ss[2] += s4.z * g; ss[3] += s4.w * g;
    }
#pragma unroll
    for (int j = 0; j < 4; ++j) {
        size_t base = kv_sum_idx(b, pq * 4 + j, v) + chunk;
        sum3[base] = sc[j];
        sum3[base + NC3] = ss[j];
    }
}

__global__ __launch_bounds__(256) void k_kv2(float* __restrict__ sum3)
{
    int g = blockIdx.x * 256 + threadIdx.x;   // B*P*V*2 = 8192 rows
    float* p = sum3 + (size_t)g * NC3;
    float run = 0.f;
    for (int i = 0; i < NC3; ++i) { float t = p[i]; p[i] = run; run += t; }
}

__global__ __launch_bounds__(256) void k_kv3(const float* __restrict__ csp,
                                             const float* __restrict__ ssp,
                                             const float* __restrict__ cqp,
                                             const float* __restrict__ sqp,
                                             const float* __restrict__ gv,
                                             const float* __restrict__ gcum,
                                             const float* __restrict__ sum3,
                                             float* __restrict__ kvr)
{
    int blk = blockIdx.x;
    int chunk = blk & (NC3 - 1), b = blk >> 7;
    int tid = threadIdx.x;
    int w = tid >> 6, lane = tid & 63;
    int v = 2 * w + (lane & 1);
    int pq = lane >> 1;
    float sc[4], ss[4];
#pragma unroll
    for (int j = 0; j < 4; ++j) {
        size_t base = kv_sum_idx(b, pq * 4 + j, v) + chunk;
        sc[j] = sum3[base];
        ss[j] = sum3[base + NC3];
    }
    const float4* c4p = (const float4*)csp;
    const float4* s4p = (const float4*)ssp;
    const float4* cq4p = (const float4*)cqp;
    const float4* sq4p = (const float4*)sqp;
    const float rsp = 0.08838834764831845f;   // 1/sqrt(128)
    int t = b * LSEQ + chunk * CL3;
    for (int i = 0; i < CL3; ++i, ++t) {
        float4 c4 = c4p[(size_t)t * 32 + pq];
        float4 s4 = s4p[(size_t)t * 32 + pq];
        float g = gv[(size_t)t * VDIM + v];
        sc[0] += c4.x * g; sc[1] += c4.y * g; sc[2] += c4.z * g; sc[3] += c4.w * g;
        ss[0] += s4.x * g; ss[1] += s4.y * g; ss[2] += s4.z * g; ss[3] += s4.w * g;
        float4 cq = cq4p[(size_t)t * 32 + pq];
        float4 sq = sq4p[(size_t)t * 32 + pq];
        float part = cq.x * sc[0] + cq.y * sc[1] + cq.z * sc[2] + cq.w * sc[3]
                   + sq.x * ss[0] + sq.y * ss[1] + sq.z * ss[2] + sq.w * ss[3];
        part += __shfl_down(part, 32, 64);
        part += __shfl_down(part, 16, 64);
        part += __shfl_down(part, 8, 64);
        part += __shfl_down(part, 4, 64);
        part += __shfl_down(part, 2, 64);
        if (lane < 2) {
            float gc = gcum[t];
            float scale = rsqrtf(fmaxf(gc, 1.0f)) * rsp;
            kvr[(size_t)t * VDIM + v] = part * scale;
        }
    }
}

// ---------------------------------------------------------------------------
// kv_out: kvr (N x 8) @ w_kv (8 x 512) + b_kv  -> combined[:, 512:1024]
// ---------------------------------------------------------------------------
__global__ __launch_bounds__(256) void k_kvout(const float* __restrict__ kvr,
                                               const float* __restrict__ wkv,
                                               const float* __restrict__ bkv,
                                               float* __restrict__ comb)
{
    int g = blockIdx.x * 256 + threadIdx.x;   // N*512
    int c = g & 511, r = g >> 9;
    const float* kr = kvr + (size_t)r * VDIM;
    float acc = bkv[c];
#pragma unroll
    for (int k = 0; k < 8; ++k) acc += kr[k] * wkv[k * DDIM + c];
    comb[(size_t)r * 1024 + 512 + c] = acc;
}

// ---------------------------------------------------------------------------
// LayerNorm over 1024, in place. One wave per row.
// ---------------------------------------------------------------------------
__global__ __launch_bounds__(256) void k_ln(float* __restrict__ comb,
                                            const float* __restrict__ gam,
                                            const float* __restrict__ bet)
{
    int wid = threadIdx.x >> 6, lane = threadIdx.x & 63;
    int row = blockIdx.x * 4 + wid;
    float4* rp = (float4*)(comb + (size_t)row * 1024);
    float4 vv[4];
    float s = 0.f, s2 = 0.f;
#pragma unroll
    for (int q = 0; q < 4; ++q) {
        vv[q] = rp[q * 64 + lane];
        s += vv[q].x + vv[q].y + vv[q].z + vv[q].w;
        s2 += vv[q].x * vv[q].x + vv[q].y * vv[q].y + vv[q].z * vv[q].z + vv[q].w * vv[q].w;
    }
    for (int m = 32; m >= 1; m >>= 1) {
        s += __shfl_xor(s, m, 64);
        s2 += __shfl_xor(s2, m, 64);
    }
    float mu = s * (1.0f / 1024.0f);
    float var = s2 * (1.0f / 1024.0f) - mu * mu;
    float inv = rsqrtf(var + 1e-5f);
#pragma unroll
    for (int q = 0; q < 4; ++q) {
        int c0 = (q * 64 + lane) * 4;
        float4 gg = *(const float4*)(gam + c0);
        float4 bb = *(const float4*)(bet + c0);
        float4 o;
        o.x = (vv[q].x - mu) * inv * gg.x + bb.x;
        o.y = (vv[q].y - mu) * inv * gg.y + bb.y;
        o.z = (vv[q].z - mu) * inv * gg.z + bb.z;
        o.w = (vv[q].w - mu) * inv * gg.w + bb.w;
        rp[q * 64 + lane] = o;
    }
}

// ---------------------------------------------------------------------------
extern "C" void kernel_launch(void* const* d_in, const int* in_sizes, int n_in,
                              void* d_out, int out_size, void* d_ws, size_t ws_size,
                              hipStream_t stream)
{
    const float* x    = (const float*)d_in[0];
    const float* pp   = (const float*)d_in[1];
    const float* msp  = (const float*)d_in[2];
    const float* w_v  = (const float*)d_in[3];
    const float* b_v  = (const float*)d_in[4];
    const float* w_o  = (const float*)d_in[5];
    const float* b_o  = (const float*)d_in[6];
    const float* w_m  = (const float*)d_in[7];
    const float* b_m  = (const float*)d_in[8];
    const float* w_q  = (const float*)d_in[9];
    const float* b_q  = (const float*)d_in[10];
    const float* w_ke = (const float*)d_in[11];
    const float* b_ke = (const float*)d_in[12];
    const float* w_ve = (const float*)d_in[13];
    const float* b_ve = (const float*)d_in[14];
    const float* w_s1 = (const float*)d_in[15];
    const float* b_s1 = (const float*)d_in[16];
    const float* w_s2 = (const float*)d_in[17];
    const float* b_s2 = (const float*)d_in[18];
    const float* w_g  = (const float*)d_in[19];
    const float* b_g  = (const float*)d_in[20];
    const float* w_kv = (const float*)d_in[21];
    const float* b_kv = (const float*)d_in[22];
    const float* ln_g = (const float*)d_in[23];
    const float* ln_b = (const float*)d_in[24];
    const float* w_t1 = (const float*)d_in[25];
    const float* b_t1 = (const float*)d_in[26];
    const float* w_t2 = (const float*)d_in[27];
    const float* b_t2 = (const float*)d_in[28];
    float* out = (float*)d_out;
    float* ws = (float*)d_ws;

    // workspace layout (floats); total 50,102,272 floats = 200.4 MB
    const size_t ND = 8388608;   // N*D
    const size_t NP = 2097152;   // N*P
    float* V1b   = ws;                     // v1; later h_s; later combined[0:]
    float* MLINb = ws + ND;                // m_lin; later sk; combined[ND:]
    float* QLINb = ws + 2 * ND;            // q_lin; later 4 phase tables (4*NP == ND)
    float* KEb   = ws + 3 * ND;            // ke_lin (NP)
    float* GVb   = KEb + NP;               // N*V
    float* GLINb = GVb + 131072;           // N
    float* GCUMb = GLINb + 16384;          // N
    float* CPHIb = GCUMb + 16384;          // L*D
    float* SPHIb = CPHIb + 2097152;        // L*D
    float* CTXb  = SPHIb + 2097152;        // ctx; later h_t[0:]
    float* PRETb = CTXb + ND;              // pos_ret; later h_t[ND:]
    float* SUM2b = PRETb + ND;             // 4*B*D*NC2 = 524288
    float* SUM3b = SUM2b + 524288;         // B*P*V*2*NC3 = 1048576
    float* KVRb  = SUM3b + 1048576;        // N*V
    float* COMBb = V1b;                    // N*2D (reuses V1+MLIN)
    float* HSb   = V1b;
    float* SKb   = MLINb;
    float* CSPb  = QLINb;
    float* SSPb  = QLINb + NP;
    float* CQPb  = QLINb + 2 * NP;
    float* SQPb  = QLINb + 3 * NP;
    float* HTb   = CTXb;                   // N*2D (reuses CTX+PRET)
    (void)ws_size; (void)n_in; (void)in_sizes; (void)out_size;

    // 1. phase tables for pos_phases
    k_phi<<<8192, 256, 0, stream>>>(pp, CPHIb, SPHIb, 2097152);

    // 2. token GEMMs on x
    gemm_f32<<<dim3(4, 128), 256, 0, stream>>>(x, 512, x, 512, 512, 512, w_v, b_v, 512, V1b, 512, 0, nullptr, 0, 0);
    gemm_f32<<<dim3(4, 128), 256, 0, stream>>>(x, 512, x, 512, 512, 512, w_m, b_m, 512, MLINb, 512, 0, nullptr, 0, 0);
    gemm_f32<<<dim3(4, 128), 256, 0, stream>>>(x, 512, x, 512, 512, 512, w_q, b_q, 512, QLINb, 512, 0, nullptr, 0, 0);
    gemm_f32<<<dim3(1, 128), 256, 0, stream>>>(x, 512, x, 512, 512, 512, w_ke, b_ke, 128, KEb, 128, 0, nullptr, 0, 0);
    k_glin<<<4096, 256, 0, stream>>>(x, w_g, b_g, GLINb);
    k_values<<<512, 256, 0, stream>>>(x, w_ve, b_ve, GLINb, GVb);

    // 3. (b,d) scans -> pos_ret, context_avg
    k_scan1a<<<512, 256, 0, stream>>>(V1b, MLINb, x, CPHIb, SPHIb, msp, SUM2b);
    k_scan1b<<<32, 256, 0, stream>>>(SUM2b);
    k_scan1c<<<512, 256, 0, stream>>>(V1b, MLINb, QLINb, x, CPHIb, SPHIb, msp, SUM2b, PRETb, CTXb);

    // 4. storage-key branch: s1 (concat x|ctx) -> gelu -> s2
    gemm_f32<<<dim3(4, 128), 256, 0, stream>>>(x, 512, CTXb, 512, 512, 1024, w_s1, b_s1, 512, HSb, 512, 0, nullptr, 0, 1);
    gemm_f32<<<dim3(1, 128), 256, 0, stream>>>(HSb, 512, HSb, 512, 512, 512, w_s2, b_s2, 128, SKb, 128, 0, nullptr, 0, 0);

    // 5. phase tables for storage/query phases; gate cumsum
    k_phases<<<8192, 256, 0, stream>>>(SKb, KEb, CSPb, SSPb, CQPb, SQPb, 2097152);
    k_gatescan<<<4, 1024, 0, stream>>>(GLINb, GCUMb);

    // 6. kv scan -> kv_retrieved
    k_kv1<<<512, 256, 0, stream>>>(CSPb, SSPb, GVb, SUM3b);
    k_kv2<<<32, 256, 0, stream>>>(SUM3b);
    k_kv3<<<512, 256, 0, stream>>>(CSPb, SSPb, CQPb, SQPb, GVb, GCUMb, SUM3b, KVRb);

    // 7. output heads into combined, LN, MLP, residual
    gemm_f32<<<dim3(4, 128), 256, 0, stream>>>(PRETb, 512, PRETb, 512, 512, 512, w_o, b_o, 512, COMBb, 1024, 0, nullptr, 0, 0);
    k_kvout<<<32768, 256, 0, stream>>>(KVRb, w_kv, b_kv, COMBb);
    k_ln<<<4096, 256, 0, stream>>>(COMBb, ln_g, ln_b);
    gemm_f32<<<dim3(8, 128), 256, 0, stream>>>(COMBb, 1024, COMBb, 1024, 1024, 1024, w_t1, b_t1, 1024, HTb, 1024, 0, nullptr, 0, 1);
    gemm_f32<<<dim3(4, 128), 256, 0, stream>>>(HTb, 1024, HTb, 1024, 1024, 1024, w_t2, b_t2, 512, out, 512, 0, x, 512, 0);
}

// Round 2
// 667.375 us; speedup vs baseline: 2.6075x; 2.6075x over previous
//
#include <hip/hip_runtime.h>
#include <math.h>

// Problem constants
#define NTOK 16384   // B*L
#define LSEQ 4096
#define BATCH 4
#define DDIM 512
#define PDIM 128
#define VDIM 8
#define PI_F 3.14159265358979323846f

// scan chunking
#define NC2 64            // chunks for (b,d) scans, chunk len 64
#define CL2 64
#define NC3 128           // chunks for kv scan, chunk len 32
#define CL3 32

typedef __attribute__((ext_vector_type(8))) short bfrag8;
typedef __attribute__((ext_vector_type(4))) float facc4;

__device__ __forceinline__ float sigmoid_(float v) { return 1.0f / (1.0f + expf(-v)); }
__device__ __forceinline__ float gelu_(float v) { return 0.5f * v * (1.0f + erff(v * 0.70710678118654752f)); }

// bf16 helpers (raw ushort storage, RNE rounding)
__device__ __forceinline__ unsigned short f2bf(float f) {
    unsigned int u = __builtin_bit_cast(unsigned int, f);
    u += 0x7fffu + ((u >> 16) & 1u);
    return (unsigned short)(u >> 16);
}
__device__ __forceinline__ float bf2f(unsigned short h) {
    return __builtin_bit_cast(float, ((unsigned int)h) << 16);
}
__device__ __forceinline__ float bflo(unsigned int w) { return __builtin_bit_cast(float, w << 16); }
__device__ __forceinline__ float bfhi(unsigned int w) { return __builtin_bit_cast(float, w & 0xffff0000u); }

// async global->LDS, 16B per lane
__device__ __forceinline__ void async16(const unsigned short* g, unsigned short* l) {
    __builtin_amdgcn_global_load_lds(
        (const __attribute__((address_space(1))) unsigned int*)g,
        (__attribute__((address_space(3))) unsigned int*)l, 16, 0, 0);
}

// ---------------------------------------------------------------------------
// bf16 MFMA GEMM: C[row, colOff+col] = act(A[row,:] @ Wt[col,:]^T + bias[col]) (+res)
// A: M x K bf16 (ldA), Wt: N x K bf16 (transposed weight, ld = K).
// Tile 128x128, BK=32, 256 threads (4 waves, 2x2), each wave 64x64 via 4x4
// mfma_f32_16x16x32_bf16. Output fp32 (Cf) or bf16 (Cb).
// ---------------------------------------------------------------------------
__global__ __launch_bounds__(256) void gemm_bf16(
    const unsigned short* __restrict__ A, int ldA,
    const unsigned short* __restrict__ Wt,
    const float* __restrict__ bias, int K,
    float* __restrict__ Cf, unsigned short* __restrict__ Cb, int ldC, int colOff,
    const float* __restrict__ res, int ldRes,
    int act)
{
    __shared__ unsigned short Asm[128 * 32];
    __shared__ unsigned short Bsm[128 * 32];
    const int tid = threadIdx.x;
    const int lane = tid & 63;
    const int wv = tid >> 6;
    const int wm = wv & 1, wn = wv >> 1;
    const int quad = lane >> 4, cc = lane & 15;
    const int row0 = blockIdx.y << 7;
    const int col0 = blockIdx.x << 7;

    facc4 acc[4][4];
#pragma unroll
    for (int i = 0; i < 4; ++i)
#pragma unroll
        for (int j = 0; j < 4; ++j) acc[i][j] = (facc4){0.f, 0.f, 0.f, 0.f};

    const int rquad = tid >> 2;      // 0..63
    const int kq = tid & 3;          // 0..3

    for (int k0 = 0; k0 < K; k0 += 32) {
        __syncthreads();
        {
            const unsigned short* ga0 = A + (size_t)(row0 + rquad) * ldA + k0 + kq * 8;
            const unsigned short* ga1 = A + (size_t)(row0 + 64 + rquad) * ldA + k0 + kq * 8;
            async16(ga0, &Asm[tid * 8]);
            async16(ga1, &Asm[(256 + tid) * 8]);
            const unsigned short* gb0 = Wt + (size_t)(col0 + rquad) * K + k0 + kq * 8;
            const unsigned short* gb1 = Wt + (size_t)(col0 + 64 + rquad) * K + k0 + kq * 8;
            async16(gb0, &Bsm[tid * 8]);
            async16(gb1, &Bsm[(256 + tid) * 8]);
        }
        __syncthreads();
        bfrag8 afr[4], bfr[4];
#pragma unroll
        for (int mt = 0; mt < 4; ++mt)
            afr[mt] = *(const bfrag8*)&Asm[(wm * 64 + mt * 16 + cc) * 32 + quad * 8];
#pragma unroll
        for (int nt = 0; nt < 4; ++nt)
            bfr[nt] = *(const bfrag8*)&Bsm[(wn * 64 + nt * 16 + cc) * 32 + quad * 8];
#pragma unroll
        for (int mt = 0; mt < 4; ++mt)
#pragma unroll
            for (int nt = 0; nt < 4; ++nt)
                acc[mt][nt] = __builtin_amdgcn_mfma_f32_16x16x32_bf16(
                    afr[mt], bfr[nt], acc[mt][nt], 0, 0, 0);
    }

#pragma unroll
    for (int nt = 0; nt < 4; ++nt) {
        int col = col0 + wn * 64 + nt * 16 + cc;
        float bvv = bias[col];
#pragma unroll
        for (int mt = 0; mt < 4; ++mt) {
            int rowb = row0 + wm * 64 + mt * 16 + quad * 4;
#pragma unroll
            for (int r = 0; r < 4; ++r) {
                float v = acc[mt][nt][r] + bvv;
                if (act == 1) v = gelu_(v);
                size_t row = (size_t)(rowb + r);
                if (res) v += res[row * ldRes + col];
                size_t idx = row * ldC + colOff + col;
                if (Cf) Cf[idx] = v;
                else    Cb[idx] = f2bf(v);
            }
        }
    }
}

// ---------------------------------------------------------------------------
// weight convert+transpose: Wt[n*K+k] = bf16(W[k*N+n]). Grid (N/32, K/32).
// ---------------------------------------------------------------------------
__global__ __launch_bounds__(256) void k_wcvt(const float* __restrict__ W, int K, int N,
                                              unsigned short* __restrict__ Wt)
{
    __shared__ float t[32][33];
    int bx = blockIdx.x, by = blockIdx.y;
    int tid = threadIdx.x;
    int tx = tid & 31, ty = tid >> 5;   // ty 0..7
#pragma unroll
    for (int r = 0; r < 4; ++r) {
        int k = by * 32 + ty + r * 8;
        t[ty + r * 8][tx] = W[(size_t)k * N + bx * 32 + tx];
    }
    __syncthreads();
#pragma unroll
    for (int r = 0; r < 4; ++r) {
        int n = bx * 32 + ty + r * 8;
        Wt[(size_t)n * K + by * 32 + tx] = f2bf(t[tx][ty + r * 8]);
    }
}

// x (N x 512 fp32) -> XCAT left half (N x 1024 bf16)
__global__ void k_xcvt(const float* __restrict__ x, unsigned short* __restrict__ xcat)
{
    int g = blockIdx.x * 256 + threadIdx.x;
    int c = g & 511, r = g >> 9;
    xcat[(size_t)r * 1024 + c] = f2bf(x[g]);
}

// ---------------------------------------------------------------------------
// cos/sin of pos_phases (L*D elements)
// ---------------------------------------------------------------------------
__global__ void k_phi(const float* __restrict__ pp, float* __restrict__ cphi,
                      float* __restrict__ sphi, int n)
{
    int i = blockIdx.x * 256 + threadIdx.x;
    if (i < n) {
        float s, c;
        sincosf(pp[i], &s, &c);
        cphi[i] = c;
        sphi[i] = s;
    }
}

// ---------------------------------------------------------------------------
// g_lin[r] = x[r,:] @ w_g + b_g   (one wave per row)
// ---------------------------------------------------------------------------
__global__ __launch_bounds__(256) void k_glin(const float* __restrict__ x,
                                              const float* __restrict__ wg,
                                              const float* __restrict__ bg,
                                              float* __restrict__ glin)
{
    int wid = threadIdx.x >> 6, lane = threadIdx.x & 63;
    int row = blockIdx.x * 4 + wid;
    const float4* xr = (const float4*)(x + (size_t)row * DDIM);
    const float4* w4 = (const float4*)wg;
    float4 a0 = xr[lane], a1 = xr[lane + 64];
    float4 w0 = w4[lane], w1 = w4[lane + 64];
    float p = a0.x * w0.x + a0.y * w0.y + a0.z * w0.z + a0.w * w0.w
            + a1.x * w1.x + a1.y * w1.y + a1.z * w1.z + a1.w * w1.w;
    for (int d = 32; d >= 1; d >>= 1) p += __shfl_down(p, d, 64);
    if (lane == 0) glin[row] = p + bg[0];
}

// ---------------------------------------------------------------------------
// gv[r,v] = (x[r,:] @ w_ve + b_ve)[v] * sigmoid(g_lin[r])
// ---------------------------------------------------------------------------
__global__ __launch_bounds__(256) void k_values(const float* __restrict__ x,
                                                const float* __restrict__ wve,
                                                const float* __restrict__ bve,
                                                const float* __restrict__ glin,
                                                float* __restrict__ gv)
{
    int g = blockIdx.x * 256 + threadIdx.x;   // N*V
    int m = g & 7, r = g >> 3;
    const float4* xr = (const float4*)(x + (size_t)r * DDIM);
    float acc = bve[m];
    for (int kq = 0; kq < 128; ++kq) {
        float4 a = xr[kq];
        int k = kq * 4;
        acc += a.x * wve[k * 8 + m] + a.y * wve[(k + 1) * 8 + m]
             + a.z * wve[(k + 2) * 8 + m] + a.w * wve[(k + 3) * 8 + m];
    }
    gv[g] = acc * sigmoid_(glin[r]);
}

// ---------------------------------------------------------------------------
// scan family 1: per (b,d) cumsums of {wv*cos, wv*sin, mag, x} — 3 passes
// v1/mlin/qlin are bf16 now.
// ---------------------------------------------------------------------------
__global__ __launch_bounds__(256) void k_scan1a(
    const unsigned short* __restrict__ v1, const unsigned short* __restrict__ mlin,
    const float* __restrict__ x,
    const float* __restrict__ cphi, const float* __restrict__ sphi,
    const float* __restrict__ msp, float* __restrict__ sum2)
{
    int g = blockIdx.x * 256 + threadIdx.x;   // B*NC2*D = 131072
    int d = g & 511;
    int rest = g >> 9;
    int chunk = rest & (NC2 - 1);
    int b = rest >> 6;
    float msabs = fabsf(msp[0]);
    size_t base = ((size_t)b * LSEQ + chunk * CL2) * DDIM + d;
    size_t pbase = ((size_t)chunk * CL2) * DDIM + d;
    float ac = 0.f, as = 0.f, am = 0.f, ax = 0.f;
    for (int i = 0; i < CL2; ++i) {
        float ml = bf2f(mlin[base]), vv = bf2f(v1[base]), xv = x[base];
        float cp = cphi[pbase], sp = sphi[pbase];
        float mag = msabs * sigmoid_(ml);
        float wv = mag * vv;
        ac += wv * cp; as += wv * sp; am += mag; ax += xv;
        base += DDIM; pbase += DDIM;
    }
    int col = (b * DDIM + d) * NC2 + chunk;   // [b][d][chunk]
    sum2[0 * 131072 + col] = ac;
    sum2[1 * 131072 + col] = as;
    sum2[2 * 131072 + col] = am;
    sum2[3 * 131072 + col] = ax;
}

__global__ __launch_bounds__(256) void k_scan1b(float* __restrict__ sum2)
{
    int g = blockIdx.x * 256 + threadIdx.x;   // 4*B*D = 8192 rows of NC2
    float* p = sum2 + (size_t)g * NC2;
    float run = 0.f;
    for (int i = 0; i < NC2; ++i) { float t = p[i]; p[i] = run; run += t; }
}

__global__ __launch_bounds__(256) void k_scan1c(
    const unsigned short* __restrict__ v1, const unsigned short* __restrict__ mlin,
    const unsigned short* __restrict__ qlin, const float* __restrict__ x,
    const float* __restrict__ cphi, const float* __restrict__ sphi,
    const float* __restrict__ msp, const float* __restrict__ sum2,
    unsigned short* __restrict__ pret, unsigned short* __restrict__ xcat)
{
    int g = blockIdx.x * 256 + threadIdx.x;
    int d = g & 511;
    int rest = g >> 9;
    int chunk = rest & (NC2 - 1);
    int b = rest >> 6;
    float msabs = fabsf(msp[0]);
    int col = (b * DDIM + d) * NC2 + chunk;
    float ac = sum2[col];
    float as = sum2[131072 + col];
    float am = sum2[2 * 131072 + col];
    float ax = sum2[3 * 131072 + col];
    size_t base = ((size_t)b * LSEQ + chunk * CL2) * DDIM + d;
    size_t pbase = ((size_t)chunk * CL2) * DDIM + d;
    int l = chunk * CL2;
    const float rsd = 0.04419417382415922f;   // 1/sqrt(512)
    for (int i = 0; i < CL2; ++i, ++l) {
        float ml = bf2f(mlin[base]), vv = bf2f(v1[base]), xv = x[base];
        float q = bf2f(qlin[base]);
        float cp = cphi[pbase], sp = sphi[pbase];
        float mag = msabs * sigmoid_(ml);
        float wv = mag * vv;
        ac += wv * cp; as += wv * sp; am += mag; ax += xv;
        float inv = rsqrtf(am + 1e-8f);
        float mc = ac * inv, msn = as * inv;
        float cq, sq;
        sincosf(q, &sq, &cq);
        float cpq = cp * cq - sp * sq;   // cos(phi+q)
        float spq = sp * cq + cp * sq;   // sin(phi+q)
        pret[base] = f2bf((mc * cpq + msn * spq) * rsd);
        size_t row = (size_t)b * LSEQ + l;
        xcat[row * 1024 + 512 + d] = f2bf(ax / (float)(l + 1));
        base += DDIM; pbase += DDIM;
    }
}

// ---------------------------------------------------------------------------
// phase tables (bf16): storage_phase (from sk fp32) and query_phase (ke bf16)
// ---------------------------------------------------------------------------
__global__ void k_phases(const float* __restrict__ sk, const unsigned short* __restrict__ ke,
                         unsigned short* __restrict__ csp, unsigned short* __restrict__ ssp,
                         unsigned short* __restrict__ cqp, unsigned short* __restrict__ sqp, int n)
{
    int g = blockIdx.x * 256 + threadIdx.x;
    if (g < n) {
        float s, c;
        float spv = tanhf(sk[g]) * PI_F;
        sincosf(spv, &s, &c);
        csp[g] = f2bf(c); ssp[g] = f2bf(s);
        float qpv = tanhf(bf2f(ke[g])) * PI_F;
        sincosf(qpv, &s, &c);
        cqp[g] = f2bf(c); sqp[g] = f2bf(s);
    }
}

// ---------------------------------------------------------------------------
// gate cumsum per batch: block-parallel scan of sigmoid(g_lin) over L=4096
// ---------------------------------------------------------------------------
__global__ __launch_bounds__(1024) void k_gatescan(const float* __restrict__ glin,
                                                   float* __restrict__ gcum)
{
    __shared__ float s[1024];
    int b = blockIdx.x, tid = threadIdx.x;
    const float* gp = glin + (size_t)b * LSEQ + tid * 4;
    float e0 = sigmoid_(gp[0]);
    float e1 = sigmoid_(gp[1]);
    float e2 = sigmoid_(gp[2]);
    float e3 = sigmoid_(gp[3]);
    float l0 = e0, l1 = l0 + e1, l2 = l1 + e2, l3 = l2 + e3;
    s[tid] = l3;
    __syncthreads();
    for (int off = 1; off < 1024; off <<= 1) {
        float t = (tid >= off) ? s[tid - off] : 0.0f;
        __syncthreads();
        s[tid] += t;
        __syncthreads();
    }
    float excl = s[tid] - l3;
    float* out = gcum + (size_t)b * LSEQ + tid * 4;
    out[0] = excl + l0; out[1] = excl + l1; out[2] = excl + l2; out[3] = excl + l3;
}

// ---------------------------------------------------------------------------
// kv scan: state (P,V) per batch. Block = (b, chunk). Wave w owns v in
// {2w,2w+1}; lane owns 4 consecutive p. sum3 layout: [b][p][v][cs][chunk].
// Phase tables bf16.
// ---------------------------------------------------------------------------
__device__ __forceinline__ size_t kv_sum_idx(int b, int p, int v) {
    return ((((size_t)b * PDIM + p) * VDIM + v) * 2) * NC3;
}

__global__ __launch_bounds__(256) void k_kv1(const unsigned short* __restrict__ csp,
                                             const unsigned short* __restrict__ ssp,
                                             const float* __restrict__ gv,
                                             float* __restrict__ sum3)
{
    int blk = blockIdx.x;                 // B*NC3 = 512
    int chunk = blk & (NC3 - 1), b = blk >> 7;
    int tid = threadIdx.x;
    int w = tid >> 6, lane = tid & 63;
    int v = 2 * w + (lane & 1);
    int pq = lane >> 1;                   // 0..31
    float sc[4] = {0, 0, 0, 0}, ss[4] = {0, 0, 0, 0};
    const uint2* c2p = (const uint2*)csp;
    const uint2* s2p = (const uint2*)ssp;
    int t = b * LSEQ + chunk * CL3;
    for (int i = 0; i < CL3; ++i, ++t) {
        uint2 cu = c2p[(size_t)t * 32 + pq];
        uint2 su = s2p[(size_t)t * 32 + pq];
        float g = gv[(size_t)t * VDIM + v];
        sc[0] += bflo(cu.x) * g; sc[1] += bfhi(cu.x) * g;
        sc[2] += bflo(cu.y) * g; sc[3] += bfhi(cu.y) * g;
        ss[0] += bflo(su.x) * g; ss[1] += bfhi(su.x) * g;
        ss[2] += bflo(su.y) * g; ss[3] += bfhi(su.y) * g;
    }
#pragma unroll
    for (int j = 0; j < 4; ++j) {
        size_t base = kv_sum_idx(b, pq * 4 + j, v) + chunk;
        sum3[base] = sc[j];
        sum3[base + NC3] = ss[j];
    }
}

__global__ __launch_bounds__(256) void k_kv2(float* __restrict__ sum3)
{
    int g = blockIdx.x * 256 + threadIdx.x;   // B*P*V*2 = 8192 rows
    float* p = sum3 + (size_t)g * NC3;
    float run = 0.f;
    for (int i = 0; i < NC3; ++i) { float t = p[i]; p[i] = run; run += t; }
}

__global__ __launch_bounds__(256) void k_kv3(const unsigned short* __restrict__ csp,
                                             const unsigned short* __restrict__ ssp,
                                             const unsigned short* __restrict__ cqp,
                                             const unsigned short* __restrict__ sqp,
                                             const float* __restrict__ gv,
                                             const float* __restrict__ gcum,
                                             const float* __restrict__ sum3,
                                             float* __restrict__ kvr)
{
    int blk = blockIdx.x;
    int chunk = blk & (NC3 - 1), b = blk >> 7;
    int tid = threadIdx.x;
    int w = tid >> 6, lane = tid & 63;
    int v = 2 * w + (lane & 1);
    int pq = lane >> 1;
    float sc[4], ss[4];
#pragma unroll
    for (int j = 0; j < 4; ++j) {
        size_t base = kv_sum_idx(b, pq * 4 + j, v) + chunk;
        sc[j] = sum3[base];
        ss[j] = sum3[base + NC3];
    }
    const uint2* c2p = (const uint2*)csp;
    const uint2* s2p = (const uint2*)ssp;
    const uint2* cq2p = (const uint2*)cqp;
    const uint2* sq2p = (const uint2*)sqp;
    const float rsp = 0.08838834764831845f;   // 1/sqrt(128)
    int t = b * LSEQ + chunk * CL3;
    for (int i = 0; i < CL3; ++i, ++t) {
        uint2 cu = c2p[(size_t)t * 32 + pq];
        uint2 su = s2p[(size_t)t * 32 + pq];
        float g = gv[(size_t)t * VDIM + v];
        sc[0] += bflo(cu.x) * g; sc[1] += bfhi(cu.x) * g;
        sc[2] += bflo(cu.y) * g; sc[3] += bfhi(cu.y) * g;
        ss[0] += bflo(su.x) * g; ss[1] += bfhi(su.x) * g;
        ss[2] += bflo(su.y) * g; ss[3] += bfhi(su.y) * g;
        uint2 qcu = cq2p[(size_t)t * 32 + pq];
        uint2 qsu = sq2p[(size_t)t * 32 + pq];
        float part = bflo(qcu.x) * sc[0] + bfhi(qcu.x) * sc[1]
                   + bflo(qcu.y) * sc[2] + bfhi(qcu.y) * sc[3]
                   + bflo(qsu.x) * ss[0] + bfhi(qsu.x) * ss[1]
                   + bflo(qsu.y) * ss[2] + bfhi(qsu.y) * ss[3];
        part += __shfl_down(part, 32, 64);
        part += __shfl_down(part, 16, 64);
        part += __shfl_down(part, 8, 64);
        part += __shfl_down(part, 4, 64);
        part += __shfl_down(part, 2, 64);
        if (lane < 2) {
            float gc = gcum[t];
            float scale = rsqrtf(fmaxf(gc, 1.0f)) * rsp;
            kvr[(size_t)t * VDIM + v] = part * scale;
        }
    }
}

// ---------------------------------------------------------------------------
// kv_out: kvr (N x 8) @ w_kv (8 x 512) + b_kv  -> combined bf16 [:, 512:1024]
// ---------------------------------------------------------------------------
__global__ __launch_bounds__(256) void k_kvout(const float* __restrict__ kvr,
                                               const float* __restrict__ wkv,
                                               const float* __restrict__ bkv,
                                               unsigned short* __restrict__ comb)
{
    int g = blockIdx.x * 256 + threadIdx.x;   // N*512
    int c = g & 511, r = g >> 9;
    const float* kr = kvr + (size_t)r * VDIM;
    float acc = bkv[c];
#pragma unroll
    for (int k = 0; k < 8; ++k) acc += kr[k] * wkv[k * DDIM + c];
    comb[(size_t)r * 1024 + 512 + c] = f2bf(acc);
}

// ---------------------------------------------------------------------------
// LayerNorm over 1024 bf16, in place. One wave per row.
// ---------------------------------------------------------------------------
__global__ __launch_bounds__(256) void k_ln(unsigned short* __restrict__ comb,
                                            const float* __restrict__ gam,
                                            const float* __restrict__ bet)
{
    int wid = threadIdx.x >> 6, lane = threadIdx.x & 63;
    int row = blockIdx.x * 4 + wid;
    unsigned int* rp = (unsigned int*)(comb + (size_t)row * 1024);
    uint4 u0 = *(uint4*)&rp[lane * 8];
    uint4 u1 = *(uint4*)&rp[lane * 8 + 4];
    unsigned int uu[8] = {u0.x, u0.y, u0.z, u0.w, u1.x, u1.y, u1.z, u1.w};
    float v[16];
    float s = 0.f, s2 = 0.f;
#pragma unroll
    for (int j = 0; j < 8; ++j) {
        v[2 * j] = bflo(uu[j]);
        v[2 * j + 1] = bfhi(uu[j]);
        s += v[2 * j] + v[2 * j + 1];
        s2 += v[2 * j] * v[2 * j] + v[2 * j + 1] * v[2 * j + 1];
    }
    for (int m = 32; m >= 1; m >>= 1) {
        s += __shfl_xor(s, m, 64);
        s2 += __shfl_xor(s2, m, 64);
    }
    float mu = s * (1.0f / 1024.0f);
    float var = s2 * (1.0f / 1024.0f) - mu * mu;
    float inv = rsqrtf(var + 1e-5f);
    int c0 = lane * 16;
    unsigned int ou[8];
#pragma unroll
    for (int j = 0; j < 8; ++j) {
        float g0 = gam[c0 + 2 * j], g1 = gam[c0 + 2 * j + 1];
        float b0 = bet[c0 + 2 * j], b1 = bet[c0 + 2 * j + 1];
        float o0 = (v[2 * j] - mu) * inv * g0 + b0;
        float o1 = (v[2 * j + 1] - mu) * inv * g1 + b1;
        ou[j] = (unsigned int)f2bf(o0) | ((unsigned int)f2bf(o1) << 16);
    }
    *(uint4*)&rp[lane * 8] = make_uint4(ou[0], ou[1], ou[2], ou[3]);
    *(uint4*)&rp[lane * 8 + 4] = make_uint4(ou[4], ou[5], ou[6], ou[7]);
}

// ---------------------------------------------------------------------------
extern "C" void kernel_launch(void* const* d_in, const int* in_sizes, int n_in,
                              void* d_out, int out_size, void* d_ws, size_t ws_size,
                              hipStream_t stream)
{
    const float* x    = (const float*)d_in[0];
    const float* pp   = (const float*)d_in[1];
    const float* msp  = (const float*)d_in[2];
    const float* w_v  = (const float*)d_in[3];
    const float* b_v  = (const float*)d_in[4];
    const float* w_o  = (const float*)d_in[5];
    const float* b_o  = (const float*)d_in[6];
    const float* w_m  = (const float*)d_in[7];
    const float* b_m  = (const float*)d_in[8];
    const float* w_q  = (const float*)d_in[9];
    const float* b_q  = (const float*)d_in[10];
    const float* w_ke = (const float*)d_in[11];
    const float* b_ke = (const float*)d_in[12];
    const float* w_ve = (const float*)d_in[13];
    const float* b_ve = (const float*)d_in[14];
    const float* w_s1 = (const float*)d_in[15];
    const float* b_s1 = (const float*)d_in[16];
    const float* w_s2 = (const float*)d_in[17];
    const float* b_s2 = (const float*)d_in[18];
    const float* w_g  = (const float*)d_in[19];
    const float* b_g  = (const float*)d_in[20];
    const float* w_kv = (const float*)d_in[21];
    const float* b_kv = (const float*)d_in[22];
    const float* ln_g = (const float*)d_in[23];
    const float* ln_b = (const float*)d_in[24];
    const float* w_t1 = (const float*)d_in[25];
    const float* b_t1 = (const float*)d_in[26];
    const float* w_t2 = (const float*)d_in[27];
    const float* b_t2 = (const float*)d_in[28];
    float* out = (float*)d_out;
    float* ws = (float*)d_ws;
    (void)ws_size; (void)n_in; (void)in_sizes; (void)out_size;

    // ---- workspace layout (float offsets); total 33,914,880 floats = 135.7 MB
    unsigned short* V1bf   = (unsigned short*)(ws);              // N*D bf16   [dead after scan1c]
    unsigned short* MLINbf = (unsigned short*)(ws + 4194304);    // N*D bf16   [dead after scan1c]
    float*          SKf    = ws + 4194304;                       // N*P fp32, reuses MLIN [dead after phases]
    unsigned short* QLINbf = (unsigned short*)(ws + 8388608);    // N*D bf16   [dead after scan1c]
    unsigned short* CSP    = (unsigned short*)(ws + 8388608);    // 4 bf16 phase tables reuse QLIN
    unsigned short* SSP    = CSP + 2097152;
    unsigned short* CQP    = CSP + 2 * 2097152;
    unsigned short* SQP    = CSP + 3 * 2097152;
    unsigned short* KEbf   = (unsigned short*)(ws + 12582912);   // N*P bf16
    float* GVb   = ws + 13631488;                                // N*V
    float* GLINb = ws + 13762560;                                // N
    float* GCUMb = ws + 13778944;                                // N
    float* SUM2b = ws + 13795328;                                // 524288
    float* SUM3b = ws + 14319616;                                // 1048576
    float* KVRb  = ws + 15368192;                                // N*V
    float* CPHIb = ws + 15499264;                                // L*D
    float* SPHIb = ws + 17596416;                                // L*D
    unsigned short* HSbf   = (unsigned short*)(ws + 15499264);   // N*D bf16, reuses CPHI+SPHI
    unsigned short* PRETbf = (unsigned short*)(ws + 19693568);   // N*D bf16 [dead after o-gemm]
    unsigned short* XCAT   = (unsigned short*)(ws + 23887872);   // N*1024 bf16 [dead after s1]
    unsigned short* COMBbf = XCAT;                               // N*1024 bf16, reuses XCAT
    unsigned short* HTbf   = (unsigned short*)(ws);              // N*1024 bf16, reuses V1+MLIN/SK
    unsigned short* WT     = (unsigned short*)(ws + 32276480);
    unsigned short* wv_t  = WT;                  // 512x512
    unsigned short* wm_t  = WT + 262144;         // 512x512
    unsigned short* wq_t  = WT + 524288;         // 512x512
    unsigned short* wo_t  = WT + 786432;         // 512x512
    unsigned short* wke_t = WT + 1048576;        // 128x512
    unsigned short* ws1_t = WT + 1114112;        // 512x1024
    unsigned short* ws2_t = WT + 1638400;        // 128x512
    unsigned short* wt1_t = WT + 1703936;        // 1024x1024
    unsigned short* wt2_t = WT + 2752512;        // 512x1024

    // 1. phase tables for pos_phases + input conversions
    k_phi<<<8192, 256, 0, stream>>>(pp, CPHIb, SPHIb, 2097152);
    k_xcvt<<<32768, 256, 0, stream>>>(x, XCAT);
    k_wcvt<<<dim3(16, 16), 256, 0, stream>>>(w_v, 512, 512, wv_t);
    k_wcvt<<<dim3(16, 16), 256, 0, stream>>>(w_m, 512, 512, wm_t);
    k_wcvt<<<dim3(16, 16), 256, 0, stream>>>(w_q, 512, 512, wq_t);
    k_wcvt<<<dim3(16, 16), 256, 0, stream>>>(w_o, 512, 512, wo_t);
    k_wcvt<<<dim3(4, 16), 256, 0, stream>>>(w_ke, 512, 128, wke_t);
    k_wcvt<<<dim3(16, 32), 256, 0, stream>>>(w_s1, 1024, 512, ws1_t);
    k_wcvt<<<dim3(4, 16), 256, 0, stream>>>(w_s2, 512, 128, ws2_t);
    k_wcvt<<<dim3(32, 32), 256, 0, stream>>>(w_t1, 1024, 1024, wt1_t);
    k_wcvt<<<dim3(16, 32), 256, 0, stream>>>(w_t2, 1024, 512, wt2_t);

    // 2. token GEMMs on x (bf16 MFMA)
    gemm_bf16<<<dim3(4, 128), 256, 0, stream>>>(XCAT, 1024, wv_t, b_v, 512, nullptr, V1bf, 512, 0, nullptr, 0, 0);
    gemm_bf16<<<dim3(4, 128), 256, 0, stream>>>(XCAT, 1024, wm_t, b_m, 512, nullptr, MLINbf, 512, 0, nullptr, 0, 0);
    gemm_bf16<<<dim3(4, 128), 256, 0, stream>>>(XCAT, 1024, wq_t, b_q, 512, nullptr, QLINbf, 512, 0, nullptr, 0, 0);
    gemm_bf16<<<dim3(1, 128), 256, 0, stream>>>(XCAT, 1024, wke_t, b_ke, 512, nullptr, KEbf, 128, 0, nullptr, 0, 0);
    k_glin<<<4096, 256, 0, stream>>>(x, w_g, b_g, GLINb);
    k_values<<<512, 256, 0, stream>>>(x, w_ve, b_ve, GLINb, GVb);

    // 3. (b,d) scans -> pos_ret (bf16), context_avg (bf16 into XCAT right half)
    k_scan1a<<<512, 256, 0, stream>>>(V1bf, MLINbf, x, CPHIb, SPHIb, msp, SUM2b);
    k_scan1b<<<32, 256, 0, stream>>>(SUM2b);
    k_scan1c<<<512, 256, 0, stream>>>(V1bf, MLINbf, QLINbf, x, CPHIb, SPHIb, msp, SUM2b, PRETbf, XCAT);

    // 4. storage-key branch: s1 (XCAT) -> gelu -> bf16 hs; s2 -> fp32 sk
    gemm_bf16<<<dim3(4, 128), 256, 0, stream>>>(XCAT, 1024, ws1_t, b_s1, 1024, nullptr, HSbf, 512, 0, nullptr, 0, 1);
    gemm_bf16<<<dim3(1, 128), 256, 0, stream>>>(HSbf, 512, ws2_t, b_s2, 512, SKf, nullptr, 128, 0, nullptr, 0, 0);

    // 5. phase tables (bf16) for storage/query; gate cumsum
    k_phases<<<8192, 256, 0, stream>>>(SKf, KEbf, CSP, SSP, CQP, SQP, 2097152);
    k_gatescan<<<4, 1024, 0, stream>>>(GLINb, GCUMb);

    // 6. kv scan -> kv_retrieved (fp32)
    k_kv1<<<512, 256, 0, stream>>>(CSP, SSP, GVb, SUM3b);
    k_kv2<<<32, 256, 0, stream>>>(SUM3b);
    k_kv3<<<512, 256, 0, stream>>>(CSP, SSP, CQP, SQP, GVb, GCUMb, SUM3b, KVRb);

    // 7. heads into combined (bf16), LN, MLP (bf16), residual fp32
    gemm_bf16<<<dim3(4, 128), 256, 0, stream>>>(PRETbf, 512, wo_t, b_o, 512, nullptr, COMBbf, 1024, 0, nullptr, 0, 0);
    k_kvout<<<32768, 256, 0, stream>>>(KVRb, w_kv, b_kv, COMBbf);
    k_ln<<<4096, 256, 0, stream>>>(COMBbf, ln_g, ln_b);
    gemm_bf16<<<dim3(8, 128), 256, 0, stream>>>(COMBbf, 1024, wt1_t, b_t1, 1024, nullptr, HTbf, 1024, 0, nullptr, 0, 1);
    gemm_bf16<<<dim3(4, 128), 256, 0, stream>>>(HTbf, 1024, wt2_t, b_t2, 1024, out, nullptr, 512, 0, x, 512, 0);
}